// Round 3
// baseline (330.292 us; speedup 1.0000x reference)
//
#include <hip/hip_runtime.h>
#include <hip/hip_bf16.h>

#define T_SEQ 2048
#define D_IN  1024
#define DH    128

typedef __attribute__((ext_vector_type(8))) short bf16x8;   // 8 bf16 in 4 VGPRs
typedef __attribute__((ext_vector_type(4))) float f32x4;

__device__ inline short f2bf(float f) {
    union { float f; unsigned u; } a; a.f = f;
    unsigned u = a.u;
    return (short)((u + 0x7fffu + ((u >> 16) & 1u)) >> 16);   // RNE
}

// ---------------- K0: W transpose -> bf16 WT[3][128][1024] ----------------
__global__ __launch_bounds__(256) void k_wt(const float* __restrict__ Wq,
                                            const float* __restrict__ Wk,
                                            const float* __restrict__ Wv,
                                            short* __restrict__ WT) {
    int idx = blockIdx.x * 256 + threadIdx.x;           // 0 .. 3*128*1024-1
    if (idx >= 3 * DH * D_IN) return;
    int m = idx >> 17;                 // which matrix
    int n = (idx >> 10) & (DH - 1);    // output col
    int k = idx & (D_IN - 1);          // input dim
    const float* W = (m == 0) ? Wq : (m == 1) ? Wk : Wv;
    WT[idx] = f2bf(W[k * DH + n]);
}

// ---------------- K1: QKV projection GEMM, BM=64 BN=128 BK=64 -------------
// grid (256 m-blocks, 3 n-groups). T14 prefetch: next chunk loads issued
// right after barrier, consumed (converted + ds_write) next iteration.
__global__ __launch_bounds__(256) void k_qkv(const float* __restrict__ x,
                                             const short* __restrict__ WT,
                                             const float* __restrict__ bq,
                                             const float* __restrict__ bk,
                                             const float* __restrict__ bv,
                                             short* __restrict__ Qb,
                                             short* __restrict__ Kb,
                                             short* __restrict__ VT) {
    __shared__ short As[64 * 72];                       // 9 KB, padded stride 72
    __shared__ short Bs[128 * 72];                      // 18 KB
    int g = blockIdx.y;
    int m0 = blockIdx.x * 64;
    int tid = threadIdx.x;
    int wv = tid >> 6, lane = tid & 63;
    int lr = lane & 15, lg = lane >> 4;
    int wm = wv >> 1, wn = wv & 1;                      // wave tile 32x64

    const short* Wg = WT + (size_t)g * DH * D_IN;
    int arow = tid >> 2, qd = tid & 3;                  // A stage: 64 rows x 4 quarters
    int brow = tid >> 1, h = tid & 1;                   // B stage: 128 rows x 2 halves

    float4 ax[4];
    uint4  bw[4];
    const float* xa = x + (size_t)(m0 + arow) * D_IN + qd * 16;
    const short* wb = Wg + (size_t)brow * D_IN + h * 32;
    // prologue loads kc=0
    ax[0] = ((const float4*)xa)[0]; ax[1] = ((const float4*)xa)[1];
    ax[2] = ((const float4*)xa)[2]; ax[3] = ((const float4*)xa)[3];
    bw[0] = ((const uint4*)wb)[0];  bw[1] = ((const uint4*)wb)[1];
    bw[2] = ((const uint4*)wb)[2];  bw[3] = ((const uint4*)wb)[3];

    const f32x4 z4 = {0.f, 0.f, 0.f, 0.f};
    f32x4 acc[2][4];
#pragma unroll
    for (int i = 0; i < 2; i++)
#pragma unroll
        for (int j = 0; j < 4; j++) acc[i][j] = z4;

    for (int kc = 0; kc < D_IN; kc += 64) {
        // convert + write staged regs to LDS
        union { short s[8]; uint4 u; } c0, c1;
#pragma unroll
        for (int e = 0; e < 4; e++) {
            c0.s[e * 2]     = f2bf(ax[e].x); c0.s[e * 2 + 1] = f2bf(ax[e].y);
            c1.s[e * 2]     = f2bf(ax[e].z); c1.s[e * 2 + 1] = f2bf(ax[e].w);
        }
        // interleave: ax[e] = cols qd*16 + e*4 .. +4 -> shorts in order
        union { short s[16]; uint4 u[2]; } cc;
#pragma unroll
        for (int e = 0; e < 4; e++) {
            cc.s[e * 4 + 0] = f2bf(ax[e].x); cc.s[e * 4 + 1] = f2bf(ax[e].y);
            cc.s[e * 4 + 2] = f2bf(ax[e].z); cc.s[e * 4 + 3] = f2bf(ax[e].w);
        }
        uint4* ad = (uint4*)&As[arow * 72 + qd * 16];
        ad[0] = cc.u[0]; ad[1] = cc.u[1];
        uint4* bd = (uint4*)&Bs[brow * 72 + h * 32];
        bd[0] = bw[0]; bd[1] = bw[1]; bd[2] = bw[2]; bd[3] = bw[3];
        __syncthreads();
        if (kc + 64 < D_IN) {                           // prefetch next chunk
            const float* xn = xa + kc + 64;
            ax[0] = ((const float4*)xn)[0]; ax[1] = ((const float4*)xn)[1];
            ax[2] = ((const float4*)xn)[2]; ax[3] = ((const float4*)xn)[3];
            const short* wn_ = wb + kc + 64;
            bw[0] = ((const uint4*)wn_)[0]; bw[1] = ((const uint4*)wn_)[1];
            bw[2] = ((const uint4*)wn_)[2]; bw[3] = ((const uint4*)wn_)[3];
        }
#pragma unroll
        for (int ks2 = 0; ks2 < 2; ks2++) {
            bf16x8 af[2], bfr[4];
#pragma unroll
            for (int mt = 0; mt < 2; mt++)
                af[mt] = *(const bf16x8*)&As[(wm * 32 + mt * 16 + lr) * 72 + ks2 * 32 + lg * 8];
#pragma unroll
            for (int nt = 0; nt < 4; nt++)
                bfr[nt] = *(const bf16x8*)&Bs[(wn * 64 + nt * 16 + lr) * 72 + ks2 * 32 + lg * 8];
#pragma unroll
            for (int mt = 0; mt < 2; mt++)
#pragma unroll
                for (int nt = 0; nt < 4; nt++)
                    acc[mt][nt] = __builtin_amdgcn_mfma_f32_16x16x32_bf16(af[mt], bfr[nt], acc[mt][nt], 0, 0, 0);
        }
        __syncthreads();
    }
    const float* bias_p = (g == 0) ? bq : (g == 1) ? bk : bv;
#pragma unroll
    for (int nt = 0; nt < 4; nt++) {
        int n = wn * 64 + nt * 16 + lr;
        float bias = bias_p[n];
#pragma unroll
        for (int mt = 0; mt < 2; mt++)
#pragma unroll
            for (int r = 0; r < 4; r++) {
                int row = m0 + wm * 32 + mt * 16 + lg * 4 + r;
                short v16 = f2bf(acc[mt][nt][r] + bias);
                if (g == 0)      Qb[(size_t)row * DH + n] = v16;
                else if (g == 1) Kb[(size_t)row * DH + n] = v16;
                else {
                    int b = row >> 11, t = row & (T_SEQ - 1);
                    VT[((size_t)b * DH + n) * T_SEQ + t] = v16;
                }
            }
    }
}

// ---- K2: per-column partial Z over a 512-wide q chunk (no max needed) ----
// grid (32 jb, 4 qs, 8 b). No LDS, no barriers: Q direct from L2.
__global__ __launch_bounds__(256) void k_stats(const short* __restrict__ Qb,
                                               const short* __restrict__ Kb,
                                               float* __restrict__ Z_part) {
    int jb = blockIdx.x, qs = blockIdx.y, b = blockIdx.z;
    int tile0 = jb * 64;
    if (qs * 512 > tile0 + 63) return;
    int tid = threadIdx.x;
    int wv = tid >> 6, lane = tid & 63;
    int lr = lane & 15, lg = lane >> 4;
    int jsub = tile0 + wv * 16;

    const short* Kp = Kb + ((size_t)b * T_SEQ + jsub + lr) * DH;
    bf16x8 kf[4];
#pragma unroll
    for (int ks = 0; ks < 4; ks++) kf[ks] = *(const bf16x8*)(Kp + ks * 32 + lg * 8);

    float Z_run[4] = {0.f, 0.f, 0.f, 0.f};
    const short* Qbase = Qb + (size_t)b * T_SEQ * DH;
    const f32x4 z4 = {0.f, 0.f, 0.f, 0.f};
    int q_lo = qs * 512;
    int q_hi = min(q_lo + 512, tile0 + 64);

    for (int qt = q_lo >> 4; qt < (q_hi >> 4); qt++) {
        f32x4 s = z4;
#pragma unroll
        for (int ks = 0; ks < 4; ks++) {
            bf16x8 qf = *(const bf16x8*)(Qbase + (size_t)(qt * 16 + lr) * DH + ks * 32 + lg * 8);
            s = __builtin_amdgcn_mfma_f32_16x16x32_bf16(kf[ks], qf, s, 0, 0, 0);
        }
        int q = qt * 16 + lr;
#pragma unroll
        for (int r = 0; r < 4; r++) {
            int j = jsub + lg * 4 + r;                  // D row = j, col = q
            Z_run[r] += (q <= j) ? __expf(s[r]) : 0.f;
        }
    }
#pragma unroll
    for (int r = 0; r < 4; r++) {
        float z = Z_run[r];
        for (int o = 1; o < 16; o <<= 1) z += __shfl_xor(z, o, 16);
        if (lr == 0)
            Z_part[((size_t)b * 4 + qs) * T_SEQ + jsub + lg * 4 + r] = z;
    }
}

// ---------------- K2b: merge partials -> 1/Z ----------------
__global__ __launch_bounds__(256) void k_sred(const float* __restrict__ Z_part,
                                              float* __restrict__ rZcol) {
    int idx = blockIdx.x * 256 + threadIdx.x;           // b*2048 + j
    int b = idx >> 11, j = idx & (T_SEQ - 1);
    int ns = j / 512 + 1;
    float Z = 0.f;
    for (int qs = 0; qs < ns; qs++)
        Z += Z_part[((size_t)b * 4 + qs) * T_SEQ + j];
    rZcol[idx] = 1.0f / Z;
}

// ---- K3: out[q][v] += sum_{j in chunk, j>=q} exp(s)/Z[j] * V[j][v] -------
// grid (32 qb, 4 js, 8 b), atomicAdd into zeroed out. T14 prefetch on K/V.
__global__ __launch_bounds__(256) void k_out(const short* __restrict__ Qb,
                                             const short* __restrict__ Kb,
                                             const short* __restrict__ VT,
                                             const float* __restrict__ rZcol,
                                             float* __restrict__ out) {
    __shared__ short klds[32 * 136];
    __shared__ short vlds[128 * 40];
    __shared__ short pbuf[4][16 * 40];
    int qb = blockIdx.x, js = blockIdx.y, b = blockIdx.z;
    int jstart = max(js * 512, qb * 64);
    int jend = (js + 1) * 512;
    if (jstart >= jend) return;

    int tid = threadIdx.x;
    int wv = tid >> 6, lane = tid & 63;
    int lr = lane & 15, lg = lane >> 4;
    int qsub = qb * 64 + wv * 16;

    const short* Qp = Qb + ((size_t)b * T_SEQ + qsub + lr) * DH;
    bf16x8 qf[4];
#pragma unroll
    for (int ks = 0; ks < 4; ks++) qf[ks] = *(const bf16x8*)(Qp + ks * 32 + lg * 8);

    const f32x4 z4 = {0.f, 0.f, 0.f, 0.f};
    f32x4 oacc[8];
#pragma unroll
    for (int i = 0; i < 8; i++) oacc[i] = z4;

    const short* Kbase = Kb + (size_t)b * T_SEQ * DH;
    const short* VTb   = VT + (size_t)b * DH * T_SEQ;
    const float* zb = rZcol + (size_t)b * T_SEQ;
    short* pw = &pbuf[wv][0];

    int krow = tid >> 3, kpart = tid & 7;
    int vrow = tid >> 1, vhalf = tid & 1;

    uint4 ka0, ka1, va0, va1;
    {
        const uint4* ksrc = (const uint4*)(Kbase + (size_t)(jstart + krow) * DH + kpart * 16);
        ka0 = ksrc[0]; ka1 = ksrc[1];
        const uint4* vsrc = (const uint4*)(VTb + (size_t)vrow * T_SEQ + jstart + vhalf * 16);
        va0 = vsrc[0]; va1 = vsrc[1];
    }

    for (int j0 = jstart; j0 < jend; j0 += 32) {
        uint4* kd = (uint4*)&klds[krow * 136 + kpart * 16];
        kd[0] = ka0; kd[1] = ka1;
        uint4* vd = (uint4*)&vlds[vrow * 40 + vhalf * 16];
        vd[0] = va0; vd[1] = va1;
        __syncthreads();
        if (j0 + 32 < jend) {                           // prefetch next tile
            const uint4* ksrc = (const uint4*)(Kbase + (size_t)(j0 + 32 + krow) * DH + kpart * 16);
            ka0 = ksrc[0]; ka1 = ksrc[1];
            const uint4* vsrc = (const uint4*)(VTb + (size_t)vrow * T_SEQ + j0 + 32 + vhalf * 16);
            va0 = vsrc[0]; va1 = vsrc[1];
        }
#pragma unroll
        for (int half = 0; half < 2; half++) {
            f32x4 s = z4;
#pragma unroll
            for (int ks = 0; ks < 4; ks++) {
                bf16x8 kfr = *(const bf16x8*)&klds[(half * 16 + lr) * 136 + ks * 32 + lg * 8];
                s = __builtin_amdgcn_mfma_f32_16x16x32_bf16(qf[ks], kfr, s, 0, 0, 0);
            }
            int j = j0 + half * 16 + lr;                // D row = q, col = j
            float rz = zb[j];
#pragma unroll
            for (int r = 0; r < 4; r++) {
                int q = qsub + lg * 4 + r;
                float p = (j >= q) ? __expf(s[r]) * rz : 0.f;
                pw[(lg * 4 + r) * 40 + half * 16 + lr] = f2bf(p);
            }
        }
        bf16x8 bp = *(const bf16x8*)&pw[lr * 40 + lg * 8];
#pragma unroll
        for (int vt = 0; vt < 8; vt++) {
            bf16x8 av = *(const bf16x8*)&vlds[(vt * 16 + lr) * 40 + lg * 8];
            oacc[vt] = __builtin_amdgcn_mfma_f32_16x16x32_bf16(av, bp, oacc[vt], 0, 0, 0);
        }
        __syncthreads();
    }
#pragma unroll
    for (int vt = 0; vt < 8; vt++)
#pragma unroll
        for (int r = 0; r < 4; r++) {
            int v = vt * 16 + lg * 4 + r;
            int q = qsub + lr;
            atomicAdd(&out[((size_t)b * T_SEQ + q) * DH + v], oacc[vt][r]);
        }
}

extern "C" void kernel_launch(void* const* d_in, const int* in_sizes, int n_in,
                              void* d_out, int out_size, void* d_ws, size_t ws_size,
                              hipStream_t stream) {
    const float* x  = (const float*)d_in[0];
    const float* Wq = (const float*)d_in[1];
    const float* bq = (const float*)d_in[2];
    const float* Wk = (const float*)d_in[3];
    const float* bk = (const float*)d_in[4];
    const float* Wv = (const float*)d_in[5];
    const float* bv = (const float*)d_in[6];
    float* out = (float*)d_out;

    char* ws = (char*)d_ws;
    short* WT = (short*)ws;                                   // 768 KB
    short* Qb = (short*)(ws + 786432);                        // 4 MB
    short* Kb = (short*)(ws + 786432 + 4194304);              // 4 MB
    short* VT = (short*)(ws + 786432 + 2 * 4194304);          // 4 MB
    float* Z_part = (float*)(ws + 786432 + 3 * 4194304);      // 256 KB
    float* rZ     = (float*)(ws + 786432 + 3 * 4194304 + 262144);

    hipMemsetAsync(out, 0, (size_t)out_size * sizeof(float), stream);
    hipLaunchKernelGGL(k_wt,   dim3(1536),     dim3(256), 0, stream, Wq, Wk, Wv, WT);
    hipLaunchKernelGGL(k_qkv,  dim3(256, 3),   dim3(256), 0, stream, x, WT, bq, bk, bv, Qb, Kb, VT);
    hipLaunchKernelGGL(k_stats,dim3(32, 4, 8), dim3(256), 0, stream, Qb, Kb, Z_part);
    hipLaunchKernelGGL(k_sred, dim3(64),       dim3(256), 0, stream, Z_part, rZ);
    hipLaunchKernelGGL(k_out,  dim3(32, 4, 8), dim3(256), 0, stream, Qb, Kb, VT, rZ, out);
}

// Round 4
// 276.119 us; speedup vs baseline: 1.1962x; 1.1962x over previous
//
#include <hip/hip_runtime.h>
#include <hip/hip_bf16.h>

#define T_SEQ 2048
#define D_IN  1024
#define DH    128

typedef __attribute__((ext_vector_type(8))) short bf16x8;   // 8 bf16 in 4 VGPRs
typedef __attribute__((ext_vector_type(4))) float f32x4;

__device__ inline short f2bf(float f) {
    union { float f; unsigned u; } a; a.f = f;
    unsigned u = a.u;
    return (short)((u + 0x7fffu + ((u >> 16) & 1u)) >> 16);   // RNE
}

#define GLL16(gsrc, ldst)                                                     \
    __builtin_amdgcn_global_load_lds(                                         \
        (const __attribute__((address_space(1))) void*)(gsrc),                \
        (__attribute__((address_space(3))) void*)(ldst), 16, 0, 0)

// ---- K0: prep. blocks [0,1536): W transpose -> WT[3][128][1024] bf16;
//          blocks [1536,9728): x f32 -> xb bf16 (8 elems/thread). ----------
__global__ __launch_bounds__(256) void k_prep(const float* __restrict__ x,
                                              const float* __restrict__ Wq,
                                              const float* __restrict__ Wk,
                                              const float* __restrict__ Wv,
                                              short* __restrict__ WT,
                                              short* __restrict__ xb) {
    int bid = blockIdx.x;
    int tid = threadIdx.x;
    if (bid < 1536) {
        int idx = bid * 256 + tid;                   // 0 .. 3*128*1024-1
        int m = idx >> 17;
        int n = (idx >> 10) & (DH - 1);
        int k = idx & (D_IN - 1);
        const float* W = (m == 0) ? Wq : (m == 1) ? Wk : Wv;
        WT[idx] = f2bf(W[k * DH + n]);
    } else {
        int i = (bid - 1536) * 256 + tid;            // 0 .. 2097151 (8 floats each)
        const float4* xs = (const float4*)x + (size_t)i * 2;
        float4 a = xs[0], b = xs[1];
        union { short s[8]; uint4 u; } c;
        c.s[0] = f2bf(a.x); c.s[1] = f2bf(a.y); c.s[2] = f2bf(a.z); c.s[3] = f2bf(a.w);
        c.s[4] = f2bf(b.x); c.s[5] = f2bf(b.y); c.s[6] = f2bf(b.z); c.s[7] = f2bf(b.w);
        ((uint4*)xb)[i] = c.u;
    }
}

// ---- K1: QKV GEMM, m97-style: BM=64 BN=128 BK=64, global_load_lds(16),
//      double-buffered LDS, 1 barrier/K-step, T2 XOR swizzle both sides. ---
__global__ __launch_bounds__(256) void k_qkv(const short* __restrict__ xb,
                                             const short* __restrict__ WT,
                                             const float* __restrict__ bq,
                                             const float* __restrict__ bk,
                                             const float* __restrict__ bv,
                                             short* __restrict__ Qb,
                                             short* __restrict__ Kb,
                                             short* __restrict__ VT) {
    __shared__ char As[2][8192];                     // 64 rows x 128 B
    __shared__ char Bs[2][16384];                    // 128 rows x 128 B
    int g = blockIdx.y;
    int m0 = blockIdx.x * 64;
    int tid = threadIdx.x;
    int wv = tid >> 6, lane = tid & 63;
    int lr = lane & 15, lg = lane >> 4;
    int wm = wv >> 1, wn = wv & 1;                   // wave tile 32(m) x 64(n)

    const char* Ab = (const char*)(xb + (size_t)m0 * D_IN);
    const char* Bb = (const char*)(WT + (size_t)g * DH * D_IN);

    // per-lane stage geometry (dest byte off = wv*1024 + i*4096 + lane*16)
    int soff0 = wv * 1024 + lane * 16;

    const f32x4 z4 = {0.f, 0.f, 0.f, 0.f};
    f32x4 acc[2][4];
#pragma unroll
    for (int i = 0; i < 2; i++)
#pragma unroll
        for (int j = 0; j < 4; j++) acc[i][j] = z4;

#define STAGE(cur, kc)                                                        \
    do {                                                                      \
        _Pragma("unroll")                                                     \
        for (int i = 0; i < 2; i++) {                                         \
            int off = soff0 + i * 4096;                                       \
            int row = off >> 7, col = off & 127;                              \
            int cun = col ^ ((row & 7) << 4);                                 \
            GLL16(Ab + (size_t)row * 2048 + (kc) * 2 + cun,                   \
                  &As[cur][wv * 1024 + i * 4096]);                            \
        }                                                                     \
        _Pragma("unroll")                                                     \
        for (int i = 0; i < 4; i++) {                                         \
            int off = soff0 + i * 4096;                                       \
            int row = off >> 7, col = off & 127;                              \
            int cun = col ^ ((row & 7) << 4);                                 \
            GLL16(Bb + (size_t)row * 2048 + (kc) * 2 + cun,                   \
                  &Bs[cur][wv * 1024 + i * 4096]);                            \
        }                                                                     \
    } while (0)

    STAGE(0, 0);
    __syncthreads();                                  // compiler drains vmcnt before barrier

    int asw = (lr & 7) << 4;                          // row&7 == lr&7 for all frag rows
    int cur = 0;
    for (int kc = 0; kc < D_IN; kc += 64) {
        if (kc + 64 < D_IN) STAGE(cur ^ 1, kc + 64);  // async next tile
#pragma unroll
        for (int ks2 = 0; ks2 < 2; ks2++) {
            int cb = (ks2 * 64 + lg * 16) ^ asw;
            bf16x8 af[2], bfr[4];
#pragma unroll
            for (int mt = 0; mt < 2; mt++)
                af[mt] = *(const bf16x8*)(&As[cur][(wm * 32 + mt * 16 + lr) * 128 + cb]);
#pragma unroll
            for (int nt = 0; nt < 4; nt++)
                bfr[nt] = *(const bf16x8*)(&Bs[cur][(wn * 64 + nt * 16 + lr) * 128 + cb]);
#pragma unroll
            for (int mt = 0; mt < 2; mt++)
#pragma unroll
                for (int nt = 0; nt < 4; nt++)
                    acc[mt][nt] = __builtin_amdgcn_mfma_f32_16x16x32_bf16(af[mt], bfr[nt], acc[mt][nt], 0, 0, 0);
        }
        __syncthreads();                              // drains staged loads + read-done
        cur ^= 1;
    }

    const float* bias_p = (g == 0) ? bq : (g == 1) ? bk : bv;
#pragma unroll
    for (int nt = 0; nt < 4; nt++) {
        int n = wn * 64 + nt * 16 + lr;
        float bias = bias_p[n];
#pragma unroll
        for (int mt = 0; mt < 2; mt++)
#pragma unroll
            for (int r = 0; r < 4; r++) {
                int row = m0 + wm * 32 + mt * 16 + lg * 4 + r;
                short v16 = f2bf(acc[mt][nt][r] + bias);
                if (g == 0)      Qb[(size_t)row * DH + n] = v16;
                else if (g == 1) Kb[(size_t)row * DH + n] = v16;
                else {
                    int b = row >> 11, t = row & (T_SEQ - 1);
                    VT[((size_t)b * DH + n) * T_SEQ + t] = v16;
                }
            }
    }
#undef STAGE
}

// ---- K2: per-column partial Z over a 512-wide q chunk (no max needed) ----
__global__ __launch_bounds__(256) void k_stats(const short* __restrict__ Qb,
                                               const short* __restrict__ Kb,
                                               float* __restrict__ Z_part) {
    int jb = blockIdx.x, qs = blockIdx.y, b = blockIdx.z;
    int tile0 = jb * 64;
    if (qs * 512 > tile0 + 63) return;
    int tid = threadIdx.x;
    int wv = tid >> 6, lane = tid & 63;
    int lr = lane & 15, lg = lane >> 4;
    int jsub = tile0 + wv * 16;

    const short* Kp = Kb + ((size_t)b * T_SEQ + jsub + lr) * DH;
    bf16x8 kf[4];
#pragma unroll
    for (int ks = 0; ks < 4; ks++) kf[ks] = *(const bf16x8*)(Kp + ks * 32 + lg * 8);

    float Z_run[4] = {0.f, 0.f, 0.f, 0.f};
    const short* Qbase = Qb + (size_t)b * T_SEQ * DH;
    const f32x4 z4 = {0.f, 0.f, 0.f, 0.f};
    int q_lo = qs * 512;
    int q_hi = min(q_lo + 512, tile0 + 64);

    for (int qt = q_lo >> 4; qt < (q_hi >> 4); qt++) {
        f32x4 s = z4;
#pragma unroll
        for (int ks = 0; ks < 4; ks++) {
            bf16x8 qf = *(const bf16x8*)(Qbase + (size_t)(qt * 16 + lr) * DH + ks * 32 + lg * 8);
            s = __builtin_amdgcn_mfma_f32_16x16x32_bf16(kf[ks], qf, s, 0, 0, 0);
        }
        int q = qt * 16 + lr;
#pragma unroll
        for (int r = 0; r < 4; r++) {
            int j = jsub + lg * 4 + r;                  // D row = j, col = q
            Z_run[r] += (q <= j) ? __expf(s[r]) : 0.f;
        }
    }
#pragma unroll
    for (int r = 0; r < 4; r++) {
        float z = Z_run[r];
        for (int o = 1; o < 16; o <<= 1) z += __shfl_xor(z, o, 16);
        if (lr == 0)
            Z_part[((size_t)b * 4 + qs) * T_SEQ + jsub + lg * 4 + r] = z;
    }
}

// ---------------- K2b: merge partials -> 1/Z ----------------
__global__ __launch_bounds__(256) void k_sred(const float* __restrict__ Z_part,
                                              float* __restrict__ rZcol) {
    int idx = blockIdx.x * 256 + threadIdx.x;           // b*2048 + j
    int b = idx >> 11, j = idx & (T_SEQ - 1);
    int ns = j / 512 + 1;
    float Z = 0.f;
    for (int qs = 0; qs < ns; qs++)
        Z += Z_part[((size_t)b * 4 + qs) * T_SEQ + j];
    rZcol[idx] = 1.0f / Z;
}

// ---- K3: out[q][v] += sum_{j in chunk, j>=q} exp(s)/Z[j] * V[j][v] -------
__global__ __launch_bounds__(256) void k_out(const short* __restrict__ Qb,
                                             const short* __restrict__ Kb,
                                             const short* __restrict__ VT,
                                             const float* __restrict__ rZcol,
                                             float* __restrict__ out) {
    __shared__ short klds[32 * 136];
    __shared__ short vlds[128 * 40];
    __shared__ short pbuf[4][16 * 40];
    int qb = blockIdx.x, js = blockIdx.y, b = blockIdx.z;
    int jstart = max(js * 512, qb * 64);
    int jend = (js + 1) * 512;
    if (jstart >= jend) return;

    int tid = threadIdx.x;
    int wv = tid >> 6, lane = tid & 63;
    int lr = lane & 15, lg = lane >> 4;
    int qsub = qb * 64 + wv * 16;

    const short* Qp = Qb + ((size_t)b * T_SEQ + qsub + lr) * DH;
    bf16x8 qf[4];
#pragma unroll
    for (int ks = 0; ks < 4; ks++) qf[ks] = *(const bf16x8*)(Qp + ks * 32 + lg * 8);

    const f32x4 z4 = {0.f, 0.f, 0.f, 0.f};
    f32x4 oacc[8];
#pragma unroll
    for (int i = 0; i < 8; i++) oacc[i] = z4;

    const short* Kbase = Kb + (size_t)b * T_SEQ * DH;
    const short* VTb   = VT + (size_t)b * DH * T_SEQ;
    const float* zb = rZcol + (size_t)b * T_SEQ;
    short* pw = &pbuf[wv][0];

    int krow = tid >> 3, kpart = tid & 7;
    int vrow = tid >> 1, vhalf = tid & 1;

    uint4 ka0, ka1, va0, va1;
    {
        const uint4* ksrc = (const uint4*)(Kbase + (size_t)(jstart + krow) * DH + kpart * 16);
        ka0 = ksrc[0]; ka1 = ksrc[1];
        const uint4* vsrc = (const uint4*)(VTb + (size_t)vrow * T_SEQ + jstart + vhalf * 16);
        va0 = vsrc[0]; va1 = vsrc[1];
    }

    for (int j0 = jstart; j0 < jend; j0 += 32) {
        uint4* kd = (uint4*)&klds[krow * 136 + kpart * 16];
        kd[0] = ka0; kd[1] = ka1;
        uint4* vd = (uint4*)&vlds[vrow * 40 + vhalf * 16];
        vd[0] = va0; vd[1] = va1;
        __syncthreads();
        if (j0 + 32 < jend) {
            const uint4* ksrc = (const uint4*)(Kbase + (size_t)(j0 + 32 + krow) * DH + kpart * 16);
            ka0 = ksrc[0]; ka1 = ksrc[1];
            const uint4* vsrc = (const uint4*)(VTb + (size_t)vrow * T_SEQ + j0 + 32 + vhalf * 16);
            va0 = vsrc[0]; va1 = vsrc[1];
        }
#pragma unroll
        for (int half = 0; half < 2; half++) {
            f32x4 s = z4;
#pragma unroll
            for (int ks = 0; ks < 4; ks++) {
                bf16x8 kfr = *(const bf16x8*)&klds[(half * 16 + lr) * 136 + ks * 32 + lg * 8];
                s = __builtin_amdgcn_mfma_f32_16x16x32_bf16(qf[ks], kfr, s, 0, 0, 0);
            }
            int j = j0 + half * 16 + lr;                // D row = q, col = j
            float rz = zb[j];
#pragma unroll
            for (int r = 0; r < 4; r++) {
                int q = qsub + lg * 4 + r;
                float p = (j >= q) ? __expf(s[r]) * rz : 0.f;
                pw[(lg * 4 + r) * 40 + half * 16 + lr] = f2bf(p);
            }
        }
        bf16x8 bp = *(const bf16x8*)&pw[lr * 40 + lg * 8];
#pragma unroll
        for (int vt = 0; vt < 8; vt++) {
            bf16x8 av = *(const bf16x8*)&vlds[(vt * 16 + lr) * 40 + lg * 8];
            oacc[vt] = __builtin_amdgcn_mfma_f32_16x16x32_bf16(av, bp, oacc[vt], 0, 0, 0);
        }
        __syncthreads();
    }
#pragma unroll
    for (int vt = 0; vt < 8; vt++)
#pragma unroll
        for (int r = 0; r < 4; r++) {
            int v = vt * 16 + lg * 4 + r;
            int q = qsub + lr;
            atomicAdd(&out[((size_t)b * T_SEQ + q) * DH + v], oacc[vt][r]);
        }
}

extern "C" void kernel_launch(void* const* d_in, const int* in_sizes, int n_in,
                              void* d_out, int out_size, void* d_ws, size_t ws_size,
                              hipStream_t stream) {
    const float* x  = (const float*)d_in[0];
    const float* Wq = (const float*)d_in[1];
    const float* bq = (const float*)d_in[2];
    const float* Wk = (const float*)d_in[3];
    const float* bk = (const float*)d_in[4];
    const float* Wv = (const float*)d_in[5];
    const float* bv = (const float*)d_in[6];
    float* out = (float*)d_out;

    char* ws = (char*)d_ws;
    short* xb = (short*)ws;                                   // 32 MB
    short* WT = (short*)(ws + 33554432);                      // 768 KB
    short* Qb = (short*)(ws + 33554432 + 786432);             // 4 MB
    short* Kb = (short*)(ws + 33554432 + 786432 + 4194304);   // 4 MB
    short* VT = (short*)(ws + 33554432 + 786432 + 2 * 4194304);
    float* Z_part = (float*)(ws + 33554432 + 786432 + 3 * 4194304);  // 256 KB
    float* rZ     = (float*)(ws + 33554432 + 786432 + 3 * 4194304 + 262144);

    hipMemsetAsync(out, 0, (size_t)out_size * sizeof(float), stream);
    hipLaunchKernelGGL(k_prep, dim3(9728),     dim3(256), 0, stream, x, Wq, Wk, Wv, WT, xb);
    hipLaunchKernelGGL(k_qkv,  dim3(256, 3),   dim3(256), 0, stream, xb, WT, bq, bk, bv, Qb, Kb, VT);
    hipLaunchKernelGGL(k_stats,dim3(32, 4, 8), dim3(256), 0, stream, Qb, Kb, Z_part);
    hipLaunchKernelGGL(k_sred, dim3(64),       dim3(256), 0, stream, Z_part, rZ);
    hipLaunchKernelGGL(k_out,  dim3(32, 4, 8), dim3(256), 0, stream, Qb, Kb, VT, rZ, out);
}